// Round 6
// baseline (97.501 us; speedup 1.0000x reference)
//
#include <hip/hip_runtime.h>

typedef __attribute__((ext_vector_type(4))) float f32x4;
typedef __attribute__((ext_vector_type(8))) __bf16 bf16x8;
typedef __attribute__((ext_vector_type(4))) unsigned short us4;
typedef __attribute__((ext_vector_type(8))) unsigned short us8;

#define DEVI static __device__ __forceinline__

constexpr int T_ = 2048, E_ = 1024, H_ = 16, D_ = 64;
#define QSCALE (0.125f * 1.44269504088896f)  /* 1/sqrt(D) * log2(e) */

DEVI unsigned short f2b(float f) {
  union { __bf16 b; unsigned short u; } c; c.b = (__bf16)f; return c.u;
}

#if __has_builtin(__builtin_amdgcn_exp2f)
DEVI float fexp2(float x) { return __builtin_amdgcn_exp2f(x); }
#else
DEVI float fexp2(float x) { return __expf(x * 0.69314718056f); }
#endif

DEVI f32x4 mfma16(bf16x8 a, bf16x8 b, f32x4 c) {
  return __builtin_amdgcn_mfma_f32_16x16x32_bf16(a, b, c, 0, 0, 0);
}

// async global->LDS, 16B per lane; lds base must be wave-uniform (HW adds lane*16)
DEVI void gl16(const void* g, void* l) {
  __builtin_amdgcn_global_load_lds(
      (const __attribute__((address_space(1))) unsigned int*)g,
      (__attribute__((address_space(3))) unsigned int*)l, 16, 0, 0);
}

// ---------------- weight conversion kernels (run once) ----------------
__launch_bounds__(256)
__global__ void wcvt_kernel(const float* __restrict__ Wq,
                            const float* __restrict__ Wk,
                            const float* __restrict__ Wv,
                            unsigned short* __restrict__ wqb,
                            unsigned short* __restrict__ wkb,
                            unsigned short* __restrict__ wvb)
{
  int blk = blockIdx.x;
  const float* src; unsigned short* dst; float s = 1.0f;
  if (blk < 64)       { src = Wq; dst = wqb; s = QSCALE; }
  else if (blk < 128) { src = Wk; dst = wkb; blk -= 64; }
  else                { src = Wv; dst = wvb; blk -= 128; }
  int i = blk * 256 + threadIdx.x;
  float4 v = *(const float4*)(src + (size_t)i * 4);
  us4 o; o[0] = f2b(v.x * s); o[1] = f2b(v.y * s); o[2] = f2b(v.z * s); o[3] = f2b(v.w * s);
  *(us4*)(dst + (size_t)i * 4) = o;
}

__launch_bounds__(256)
__global__ void wpcvt_kernel(const float* __restrict__ Wp,
                             unsigned short* __restrict__ wpb)
{
  int i = blockIdx.x * 256 + threadIdx.x;
  float4 v = *(const float4*)(Wp + (size_t)i * 4);
  us4 o; o[0] = f2b(v.x); o[1] = f2b(v.y); o[2] = f2b(v.z); o[3] = f2b(v.w);
  *(us4*)(wpb + (size_t)i * 4) = o;
}

// ---------------- QKV projection ----------------
// grid: (B*H=32, T/64=32), block 256 (4 waves x 16 rows); 36KB LDS -> 4 blocks/CU
__launch_bounds__(256)
__global__ void qkv_kernel(const float* __restrict__ x,
                           const unsigned short* __restrict__ wqb,
                           const float* __restrict__ bq,
                           const unsigned short* __restrict__ wkb,
                           const float* __restrict__ bk,
                           const unsigned short* __restrict__ wvb,
                           const float* __restrict__ bv,
                           unsigned short* __restrict__ qo,
                           unsigned short* __restrict__ ko,
                           unsigned short* __restrict__ vto)
{
  const int bh = blockIdx.x;
  const int b  = bh >> 4;
  const int h  = bh & (H_ - 1);
  const int t0 = blockIdx.y * 64;
  __shared__ unsigned short Xl[64][72];
  __shared__ unsigned short Wl[3][64][72];
  const int tid = threadIdx.x;

  // stage X slice (64 x 64), f32 -> bf16
  #pragma unroll
  for (int p = 0; p < 4; ++p) {
    int idx = p * 256 + tid;
    int row = idx >> 4, c4 = idx & 15;
    float4 v = *(const float4*)(x + ((size_t)(b * T_ + t0 + row)) * E_ + h * 64 + c4 * 4);
    us4 o; o[0] = f2b(v.x); o[1] = f2b(v.y); o[2] = f2b(v.z); o[3] = f2b(v.w);
    *(us4*)&Xl[row][c4 * 4] = o;
  }
  // stage pre-converted bf16 W blocks for this head (64x64 each)
  {
    const unsigned short* wsrc0 = wqb + (size_t)h * 4096;
    const unsigned short* wsrc1 = wkb + (size_t)h * 4096;
    const unsigned short* wsrc2 = wvb + (size_t)h * 4096;
    #pragma unroll
    for (int p = 0; p < 2; ++p) {
      int idx = p * 256 + tid;
      int row = idx >> 3, c8 = (idx & 7) * 8;
      *(us8*)&Wl[0][row][c8] = *(const us8*)(wsrc0 + row * 64 + c8);
      *(us8*)&Wl[1][row][c8] = *(const us8*)(wsrc1 + row * 64 + c8);
      *(us8*)&Wl[2][row][c8] = *(const us8*)(wsrc2 + row * 64 + c8);
    }
  }
  __syncthreads();

  const int w = tid >> 6, lane = tid & 63, lo = lane & 15, g = lane >> 4;
  const int tl0 = w * 16;

  bf16x8 xb[2];
  #pragma unroll
  for (int kd = 0; kd < 2; ++kd)
    xb[kd] = *(const bf16x8*)&Xl[tl0 + lo][kd * 32 + g * 8];

  // Q and K: C = W * X^T  (o x t); store row-major q[t][o]
  #pragma unroll
  for (int tsel = 0; tsel < 2; ++tsel) {
    const float* bias = tsel ? bk : bq;
    unsigned short* outp = tsel ? ko : qo;
    const float bs = tsel ? 1.0f : QSCALE;
    #pragma unroll
    for (int ot = 0; ot < 4; ++ot) {
      bf16x8 a0 = *(const bf16x8*)&Wl[tsel][ot * 16 + lo][g * 8];
      bf16x8 a1 = *(const bf16x8*)&Wl[tsel][ot * 16 + lo][32 + g * 8];
      float4 bv4 = *(const float4*)(bias + h * 64 + ot * 16 + g * 4);
      f32x4 acc = {0.f, 0.f, 0.f, 0.f};
      acc = mfma16(a0, xb[0], acc);
      acc = mfma16(a1, xb[1], acc);
      int tg = t0 + tl0 + lo;
      us4 pk;
      pk[0] = f2b(acc[0] + bv4.x * bs); pk[1] = f2b(acc[1] + bv4.y * bs);
      pk[2] = f2b(acc[2] + bv4.z * bs); pk[3] = f2b(acc[3] + bv4.w * bs);
      *(us4*)(outp + ((size_t)(bh * T_ + tg)) * 64 + ot * 16 + g * 4) = pk;
    }
  }

  // V: C = X * W^T (t x o); store transposed vt[(bh*64+d)*T + t]
  {
    bf16x8 a0 = *(const bf16x8*)&Xl[tl0 + lo][g * 8];
    bf16x8 a1 = *(const bf16x8*)&Xl[tl0 + lo][32 + g * 8];
    #pragma unroll
    for (int ct = 0; ct < 4; ++ct) {
      bf16x8 b0 = *(const bf16x8*)&Wl[2][ct * 16 + lo][g * 8];
      bf16x8 b1 = *(const bf16x8*)&Wl[2][ct * 16 + lo][32 + g * 8];
      f32x4 acc = {0.f, 0.f, 0.f, 0.f};
      acc = mfma16(a0, b0, acc);
      acc = mfma16(a1, b1, acc);
      int d = ct * 16 + lo;
      float bvs = bv[h * 64 + d];
      int tg = t0 + tl0 + g * 4;
      us4 pk;
      #pragma unroll
      for (int r = 0; r < 4; ++r) pk[r] = f2b(acc[r] + bvs);
      *(us4*)(vto + ((size_t)(bh * 64 + d)) * T_ + tg) = pk;
    }
  }
}

// ---------------- causal flash attention ----------------
// grid: (B*H=32, 16), block 256 = 4 waves x 32 q-rows (2 cols/lane), 128-row tile.
// CU-paired balance: co-resident blocks y and y+8 have qt summing to 15 (34 steps).
// K/V staged via global_load_lds (linear LDS dest, pre-swizzled global source);
// reads XOR-deswizzle. One barrier per step. P via swizzled LDS.
__launch_bounds__(256)
__global__ void flash_kernel(const unsigned short* __restrict__ q,
                             const unsigned short* __restrict__ kk_,
                             const unsigned short* __restrict__ vt,
                             unsigned short* __restrict__ ao)
{
  const int bh = blockIdx.x;
  const int b = bh >> 4, h = bh & 15;
  const int y = blockIdx.y;
  const int qt = (y < 8) ? y : 23 - y;
  const int t0 = qt * 128;
  __shared__ unsigned short Kl[2][64][64];
  __shared__ unsigned short Vl[2][64][64];
  __shared__ unsigned short Pl[4][32][64];
  const int tid = threadIdx.x, w = tid >> 6, lane = tid & 63, lo = lane & 15, g = lane >> 4;
  const int rs = lo & 7;

  // DMA staging: LDS rows tid>>3 (and +32), granule tid&7 linear; global granule pre-swizzled
  const int srow = tid >> 3, sgi = (tid & 7) ^ ((tid >> 3) & 7);
  const unsigned short* kg0 = kk_ + ((size_t)bh * T_ + srow) * 64 + sgi * 8;
  const unsigned short* kg1 = kg0 + 32 * 64;
  const unsigned short* vg0 = vt + ((size_t)(bh * 64 + srow)) * T_ + sgi * 8;
  const unsigned short* vg1 = vg0 + (size_t)32 * T_;

  const int tw = t0 + w * 32;

  bf16x8 qf[2][2];
  const unsigned short* qb = q + ((size_t)(bh * T_ + tw)) * 64;
  #pragma unroll
  for (int tt = 0; tt < 2; ++tt)
    #pragma unroll
    for (int kd = 0; kd < 2; ++kd)
      qf[tt][kd] = *(const bf16x8*)(qb + (size_t)(tt * 16 + lo) * 64 + kd * 32 + g * 8);

  float m_[2] = {-1e30f, -1e30f};
  float l_[2] = {0.f, 0.f};
  f32x4 zero4 = {0.f, 0.f, 0.f, 0.f};
  f32x4 oacc[4][2];
  #pragma unroll
  for (int dt = 0; dt < 4; ++dt)
    #pragma unroll
    for (int tt = 0; tt < 2; ++tt) oacc[dt][tt] = zero4;

  const int nsteps = 2 * qt + 2;
  // prologue: DMA step 0 into buffer 0
  gl16(kg0, &Kl[0][w * 8][0]);
  gl16(kg1, &Kl[0][32 + w * 8][0]);
  gl16(vg0, &Vl[0][w * 8][0]);
  gl16(vg1, &Vl[0][32 + w * 8][0]);
  __syncthreads();

  for (int stp = 0; stp < nsteps; ++stp) {
    const int s0 = stp * 64;
    const int cur = stp & 1;
    if (stp + 1 < nsteps) {  // DMA next tile into other buffer (overlaps compute)
      const int nb = cur ^ 1;
      const size_t so = (size_t)(s0 + 64);
      gl16(kg0 + so * 64, &Kl[nb][w * 8][0]);
      gl16(kg1 + so * 64, &Kl[nb][32 + w * 8][0]);
      gl16(vg0 + so, &Vl[nb][w * 8][0]);
      gl16(vg1 + so, &Vl[nb][32 + w * 8][0]);
    }
    if (s0 <= tw + 31) {
      // S^T = K * Q^T : cols t = tw + tt*16 + lo, rows s = s0 + ss*16 + g*4 + r
      f32x4 sacc[4][2];
      #pragma unroll
      for (int ss = 0; ss < 4; ++ss)
        #pragma unroll
        for (int tt = 0; tt < 2; ++tt) sacc[ss][tt] = zero4;
      __builtin_amdgcn_s_setprio(1);
      #pragma unroll
      for (int ss = 0; ss < 4; ++ss) {
        bf16x8 ka0 = *(const bf16x8*)&Kl[cur][ss * 16 + lo][(g ^ rs) * 8];
        bf16x8 ka1 = *(const bf16x8*)&Kl[cur][ss * 16 + lo][((g | 4) ^ rs) * 8];
        #pragma unroll
        for (int tt = 0; tt < 2; ++tt) {
          sacc[ss][tt] = mfma16(ka0, qf[tt][0], sacc[ss][tt]);
          sacc[ss][tt] = mfma16(ka1, qf[tt][1], sacc[ss][tt]);
        }
      }
      __builtin_amdgcn_s_setprio(0);
      if (s0 + 63 > tw) {  // diagonal: causal mask
        #pragma unroll
        for (int ss = 0; ss < 4; ++ss)
          #pragma unroll
          for (int tt = 0; tt < 2; ++tt)
            #pragma unroll
            for (int r = 0; r < 4; ++r) {
              int sg = s0 + ss * 16 + g * 4 + r;
              if (sg > tw + tt * 16 + lo) sacc[ss][tt][r] = -1e30f;
            }
      }
      // online softmax (base 2), defer-max (T13)
      float mx[2];
      #pragma unroll
      for (int tt = 0; tt < 2; ++tt) {
        float a = fmaxf(fmaxf(sacc[0][tt][0], sacc[0][tt][1]), fmaxf(sacc[0][tt][2], sacc[0][tt][3]));
        float b2 = fmaxf(fmaxf(sacc[1][tt][0], sacc[1][tt][1]), fmaxf(sacc[1][tt][2], sacc[1][tt][3]));
        float c = fmaxf(fmaxf(sacc[2][tt][0], sacc[2][tt][1]), fmaxf(sacc[2][tt][2], sacc[2][tt][3]));
        float d = fmaxf(fmaxf(sacc[3][tt][0], sacc[3][tt][1]), fmaxf(sacc[3][tt][2], sacc[3][tt][3]));
        float m = fmaxf(fmaxf(a, b2), fmaxf(c, d));
        m = fmaxf(m, __shfl_xor(m, 16));
        m = fmaxf(m, __shfl_xor(m, 32));
        mx[tt] = m;
      }
      if (!__all((mx[0] <= m_[0] + 8.0f) && (mx[1] <= m_[1] + 8.0f))) {
        #pragma unroll
        for (int tt = 0; tt < 2; ++tt) {
          float mn = fmaxf(m_[tt], mx[tt]);
          float corr = fexp2(m_[tt] - mn);
          m_[tt] = mn;
          l_[tt] *= corr;
          #pragma unroll
          for (int dt = 0; dt < 4; ++dt) oacc[dt][tt] *= corr;
        }
      }
      #pragma unroll
      for (int tt = 0; tt < 2; ++tt) {
        float sum = 0.f;
        #pragma unroll
        for (int ss = 0; ss < 4; ++ss) {
          us4 pk;
          #pragma unroll
          for (int r = 0; r < 4; ++r) {
            float pv = fexp2(sacc[ss][tt][r] - m_[tt]);
            sum += pv;
            pk[r] = f2b(pv);
          }
          *(us4*)&Pl[w][tt * 16 + lo][(((ss * 2 + (g >> 1)) ^ rs) << 3) + (g & 1) * 4] = pk;
        }
        sum += __shfl_xor(sum, 16);
        sum += __shfl_xor(sum, 32);
        l_[tt] += sum;
      }
      // O^T += Vt * P^T
      __builtin_amdgcn_s_setprio(1);
      #pragma unroll
      for (int kh = 0; kh < 2; ++kh) {
        bf16x8 pb[2];
        #pragma unroll
        for (int tt = 0; tt < 2; ++tt)
          pb[tt] = *(const bf16x8*)&Pl[w][tt * 16 + lo][((kh * 4 + g) ^ rs) * 8];
        #pragma unroll
        for (int dt = 0; dt < 4; ++dt) {
          bf16x8 va = *(const bf16x8*)&Vl[cur][dt * 16 + lo][((kh * 4 + g) ^ rs) * 8];
          #pragma unroll
          for (int tt = 0; tt < 2; ++tt)
            oacc[dt][tt] = mfma16(va, pb[tt], oacc[dt][tt]);
        }
      }
      __builtin_amdgcn_s_setprio(0);
    }
    __syncthreads();  // drains DMA (vmcnt) + protects buffer swap
  }
  // epilogue
  #pragma unroll
  for (int tt = 0; tt < 2; ++tt) {
    float inv = 1.0f / l_[tt];
    unsigned short* op = ao + ((size_t)(b * T_ + tw + tt * 16 + lo)) * E_ + h * 64;
    #pragma unroll
    for (int dt = 0; dt < 4; ++dt) {
      us4 pk;
      #pragma unroll
      for (int r = 0; r < 4; ++r) pk[r] = f2b(oacc[dt][tt][r] * inv);
      *(us4*)(op + dt * 16 + g * 4) = pk;
    }
  }
}

// ---------------- output projection: out = AO * Wp^T + bp ----------------
__launch_bounds__(256)
__global__ void proj_kernel(const unsigned short* __restrict__ ao,
                            const unsigned short* __restrict__ wpb,
                            const float* __restrict__ bp,
                            float* __restrict__ out)
{
  const int m0 = blockIdx.x * 128;
  const int n0 = blockIdx.y * 64;
  __shared__ unsigned short Al[2][128][40];
  __shared__ unsigned short Bl[2][64][40];
  const int tid = threadIdx.x, w = tid >> 6, lane = tid & 63, lo = lane & 15, g = lane >> 4;
  const int wr = (w >> 1) * 64, wc = (w & 1) * 32;
  f32x4 zero4 = {0.f, 0.f, 0.f, 0.f};
  f32x4 acc[4][2];
  #pragma unroll
  for (int i = 0; i < 4; ++i)
    #pragma unroll
    for (int j = 0; j < 2; ++j) acc[i][j] = zero4;

  const int arow = tid >> 1, acol = (tid & 1) * 16;
  const int brow = tid >> 2, bcol = (tid & 3) * 8;
  const unsigned short* abase = ao + (size_t)(m0 + arow) * 1024 + acol;
  const unsigned short* bbase = wpb + (size_t)(n0 + brow) * 1024 + bcol;

  us8 a0 = *(const us8*)(abase);
  us8 a1 = *(const us8*)(abase + 8);
  us8 b0 = *(const us8*)(bbase);
  *(us8*)&Al[0][arow][acol] = a0;
  *(us8*)&Al[0][arow][acol + 8] = a1;
  *(us8*)&Bl[0][brow][bcol] = b0;
  a0 = *(const us8*)(abase + 32);
  a1 = *(const us8*)(abase + 40);
  b0 = *(const us8*)(bbase + 32);
  __syncthreads();

  for (int it = 0; it < 32; ++it) {
    const int cur = it & 1;
    us8 na0, na1, nb0;
    const bool pf = (it + 2 < 32);
    if (pf) {
      const int kn = (it + 2) * 32;
      na0 = *(const us8*)(abase + kn);
      na1 = *(const us8*)(abase + kn + 8);
      nb0 = *(const us8*)(bbase + kn);
    }
    bf16x8 af[4], bfr[2];
    #pragma unroll
    for (int i = 0; i < 4; ++i) af[i] = *(const bf16x8*)&Al[cur][wr + i * 16 + lo][g * 8];
    #pragma unroll
    for (int j = 0; j < 2; ++j) bfr[j] = *(const bf16x8*)&Bl[cur][wc + j * 16 + lo][g * 8];
    __builtin_amdgcn_s_setprio(1);
    #pragma unroll
    for (int i = 0; i < 4; ++i)
      #pragma unroll
      for (int j = 0; j < 2; ++j)
        acc[i][j] = mfma16(af[i], bfr[j], acc[i][j]);
    __builtin_amdgcn_s_setprio(0);
    if (it + 1 < 32) {
      *(us8*)&Al[cur ^ 1][arow][acol] = a0;
      *(us8*)&Al[cur ^ 1][arow][acol + 8] = a1;
      *(us8*)&Bl[cur ^ 1][brow][bcol] = b0;
    }
    __syncthreads();
    if (pf) { a0 = na0; a1 = na1; b0 = nb0; }
  }
  #pragma unroll
  for (int j = 0; j < 2; ++j) {
    int n = n0 + wc + j * 16 + lo;
    float bias = bp[n];
    #pragma unroll
    for (int i = 0; i < 4; ++i) {
      #pragma unroll
      for (int r = 0; r < 4; ++r)
        out[(size_t)(m0 + wr + i * 16 + g * 4 + r) * 1024 + n] = acc[i][j][r] + bias;
    }
  }
}

extern "C" void kernel_launch(void* const* d_in, const int* in_sizes, int n_in,
                              void* d_out, int out_size, void* d_ws, size_t ws_size,
                              hipStream_t stream)
{
  const float* x  = (const float*)d_in[0];
  const float* Wq = (const float*)d_in[2];
  const float* bq = (const float*)d_in[3];
  const float* Wk = (const float*)d_in[4];
  const float* bk = (const float*)d_in[5];
  const float* Wv = (const float*)d_in[6];
  const float* bv = (const float*)d_in[7];
  const float* Wp = (const float*)d_in[8];
  const float* bp = (const float*)d_in[9];
  float* out = (float*)d_out;

  char* ws = (char*)d_ws;
  const size_t SZ = (size_t)2 * 16 * 2048 * 64 * 2;  // 8 MB per bf16 tensor
  unsigned short* q  = (unsigned short*)(ws);
  unsigned short* kb = (unsigned short*)(ws + SZ);
  unsigned short* vt = (unsigned short*)(ws + 2 * SZ);
  unsigned short* ao = (unsigned short*)(ws + 3 * SZ);
  unsigned short* wqb = ao;                  // overlay: qkv reads before flash writes ao
  unsigned short* wkb = ao + 65536;
  unsigned short* wvb = ao + 131072;
  unsigned short* wpb = q;                   // overlay: wpcvt runs after flash read q

  wcvt_kernel<<<dim3(192), 256, 0, stream>>>(Wq, Wk, Wv, wqb, wkb, wvb);
  qkv_kernel<<<dim3(32, 32), 256, 0, stream>>>(x, wqb, bq, wkb, bk, wvb, bv, q, kb, vt);
  flash_kernel<<<dim3(32, 16), 256, 0, stream>>>(q, kb, vt, ao);
  wpcvt_kernel<<<dim3(1024), 256, 0, stream>>>(Wp, wpb);
  proj_kernel<<<dim3(32, 16), 256, 0, stream>>>(ao, wpb, bp, out);
}

// Round 7
// 84.026 us; speedup vs baseline: 1.1604x; 1.1604x over previous
//
#include <hip/hip_runtime.h>

typedef __attribute__((ext_vector_type(4))) float f32x4;
typedef __attribute__((ext_vector_type(8))) __bf16 bf16x8;
typedef __attribute__((ext_vector_type(4))) unsigned short us4;
typedef __attribute__((ext_vector_type(8))) unsigned short us8;

#define DEVI static __device__ __forceinline__

constexpr int T_ = 2048, E_ = 1024, H_ = 16, D_ = 64;
#define QSCALE (0.125f * 1.44269504088896f)  /* 1/sqrt(D) * log2(e) */

DEVI unsigned short f2b(float f) {
  union { __bf16 b; unsigned short u; } c; c.b = (__bf16)f; return c.u;
}

#if __has_builtin(__builtin_amdgcn_exp2f)
DEVI float fexp2(float x) { return __builtin_amdgcn_exp2f(x); }
#else
DEVI float fexp2(float x) { return __expf(x * 0.69314718056f); }
#endif

DEVI f32x4 mfma16(bf16x8 a, bf16x8 b, f32x4 c) {
  return __builtin_amdgcn_mfma_f32_16x16x32_bf16(a, b, c, 0, 0, 0);
}

// ---------------- weight conversion kernels (run once) ----------------
__launch_bounds__(256)
__global__ void wcvt_kernel(const float* __restrict__ Wq,
                            const float* __restrict__ Wk,
                            const float* __restrict__ Wv,
                            unsigned short* __restrict__ wqb,
                            unsigned short* __restrict__ wkb,
                            unsigned short* __restrict__ wvb)
{
  int blk = blockIdx.x;
  const float* src; unsigned short* dst; float s = 1.0f;
  if (blk < 64)       { src = Wq; dst = wqb; s = QSCALE; }
  else if (blk < 128) { src = Wk; dst = wkb; blk -= 64; }
  else                { src = Wv; dst = wvb; blk -= 128; }
  int i = blk * 256 + threadIdx.x;
  float4 v = *(const float4*)(src + (size_t)i * 4);
  us4 o; o[0] = f2b(v.x * s); o[1] = f2b(v.y * s); o[2] = f2b(v.z * s); o[3] = f2b(v.w * s);
  *(us4*)(dst + (size_t)i * 4) = o;
}

__launch_bounds__(256)
__global__ void wpcvt_kernel(const float* __restrict__ Wp,
                             unsigned short* __restrict__ wpb)
{
  int i = blockIdx.x * 256 + threadIdx.x;
  float4 v = *(const float4*)(Wp + (size_t)i * 4);
  us4 o; o[0] = f2b(v.x); o[1] = f2b(v.y); o[2] = f2b(v.z); o[3] = f2b(v.w);
  *(us4*)(wpb + (size_t)i * 4) = o;
}

// ---------------- QKV projection (r5 verbatim) ----------------
// grid: (B*H=32, T/128=16), block 256 (4 waves x 32 rows); bf16 weights
__launch_bounds__(256)
__global__ void qkv_kernel(const float* __restrict__ x,
                           const unsigned short* __restrict__ wqb,
                           const float* __restrict__ bq,
                           const unsigned short* __restrict__ wkb,
                           const float* __restrict__ bk,
                           const unsigned short* __restrict__ wvb,
                           const float* __restrict__ bv,
                           unsigned short* __restrict__ qo,
                           unsigned short* __restrict__ ko,
                           unsigned short* __restrict__ vto)
{
  const int bh = blockIdx.x;
  const int b  = bh >> 4;
  const int h  = bh & (H_ - 1);
  const int t0 = blockIdx.y * 128;
  __shared__ unsigned short Xl[128][72];
  __shared__ unsigned short Wl[3][64][72];
  const int tid = threadIdx.x;

  #pragma unroll
  for (int p = 0; p < 8; ++p) {
    int idx = p * 256 + tid;
    int row = idx >> 4, c4 = idx & 15;
    float4 v = *(const float4*)(x + ((size_t)(b * T_ + t0 + row)) * E_ + h * 64 + c4 * 4);
    us4 o; o[0] = f2b(v.x); o[1] = f2b(v.y); o[2] = f2b(v.z); o[3] = f2b(v.w);
    *(us4*)&Xl[row][c4 * 4] = o;
  }
  {
    const unsigned short* wsrc0 = wqb + (size_t)h * 4096;
    const unsigned short* wsrc1 = wkb + (size_t)h * 4096;
    const unsigned short* wsrc2 = wvb + (size_t)h * 4096;
    #pragma unroll
    for (int p = 0; p < 2; ++p) {
      int idx = p * 256 + tid;
      int row = idx >> 3, c8 = (idx & 7) * 8;
      *(us8*)&Wl[0][row][c8] = *(const us8*)(wsrc0 + row * 64 + c8);
      *(us8*)&Wl[1][row][c8] = *(const us8*)(wsrc1 + row * 64 + c8);
      *(us8*)&Wl[2][row][c8] = *(const us8*)(wsrc2 + row * 64 + c8);
    }
  }
  __syncthreads();

  const int w = tid >> 6, lane = tid & 63, lo = lane & 15, g = lane >> 4;
  const int tl0 = w * 32;

  bf16x8 xb[2][2];
  #pragma unroll
  for (int tt = 0; tt < 2; ++tt)
    #pragma unroll
    for (int kd = 0; kd < 2; ++kd)
      xb[tt][kd] = *(const bf16x8*)&Xl[tl0 + tt * 16 + lo][kd * 32 + g * 8];

  #pragma unroll
  for (int tsel = 0; tsel < 2; ++tsel) {
    const float* bias = tsel ? bk : bq;
    unsigned short* outp = tsel ? ko : qo;
    const float bs = tsel ? 1.0f : QSCALE;
    #pragma unroll
    for (int ot = 0; ot < 4; ++ot) {
      bf16x8 a0 = *(const bf16x8*)&Wl[tsel][ot * 16 + lo][g * 8];
      bf16x8 a1 = *(const bf16x8*)&Wl[tsel][ot * 16 + lo][32 + g * 8];
      float4 bv4 = *(const float4*)(bias + h * 64 + ot * 16 + g * 4);
      float bb[4] = {bv4.x * bs, bv4.y * bs, bv4.z * bs, bv4.w * bs};
      #pragma unroll
      for (int tt = 0; tt < 2; ++tt) {
        f32x4 acc = {0.f, 0.f, 0.f, 0.f};
        acc = mfma16(a0, xb[tt][0], acc);
        acc = mfma16(a1, xb[tt][1], acc);
        int tg = t0 + tl0 + tt * 16 + lo;
        us4 pk;
        #pragma unroll
        for (int r = 0; r < 4; ++r) pk[r] = f2b(acc[r] + bb[r]);
        *(us4*)(outp + ((size_t)(bh * T_ + tg)) * 64 + ot * 16 + g * 4) = pk;
      }
    }
  }

  #pragma unroll
  for (int rt = 0; rt < 2; ++rt) {
    bf16x8 a0 = *(const bf16x8*)&Xl[tl0 + rt * 16 + lo][g * 8];
    bf16x8 a1 = *(const bf16x8*)&Xl[tl0 + rt * 16 + lo][32 + g * 8];
    #pragma unroll
    for (int ct = 0; ct < 4; ++ct) {
      bf16x8 b0 = *(const bf16x8*)&Wl[2][ct * 16 + lo][g * 8];
      bf16x8 b1 = *(const bf16x8*)&Wl[2][ct * 16 + lo][32 + g * 8];
      f32x4 acc = {0.f, 0.f, 0.f, 0.f};
      acc = mfma16(a0, b0, acc);
      acc = mfma16(a1, b1, acc);
      int d = ct * 16 + lo;
      float bvs = bv[h * 64 + d];
      int tg = t0 + tl0 + rt * 16 + g * 4;
      us4 pk;
      #pragma unroll
      for (int r = 0; r < 4; ++r) pk[r] = f2b(acc[r] + bvs);
      *(us4*)(vto + ((size_t)(bh * 64 + d)) * T_ + tg) = pk;
    }
  }
}

// ---------------- causal flash attention (r5 base + T15 deferred PV) ----------------
// grid: (B*H=32, 16), block 256 = 4 waves x 16 q-rows, 64-row q-tile.
// Block y does q-tiles y and 31-y (33 steps total, balanced; 2 blocks/CU).
// Step i issues QK^T(i) and PV(i-1) as one MFMA cluster; softmax(i) VALU
// overlaps their execution. V triple-buffered (V(i-1) alive during staging
// of V(i+1)); P round-trips wave-private LDS, read back in-step for next PV.
__launch_bounds__(256)
__global__ void flash_kernel(const unsigned short* __restrict__ q,
                             const unsigned short* __restrict__ kk_,
                             const unsigned short* __restrict__ vt,
                             unsigned short* __restrict__ ao)
{
  const int bh = blockIdx.x;
  const int b = bh >> 4, h = bh & 15;
  __shared__ unsigned short Kl[2][64][64];
  __shared__ unsigned short Vl[3][64][64];
  __shared__ unsigned short Pl[4][16][64];
  const int tid = threadIdx.x, w = tid >> 6, lane = tid & 63, lo = lane & 15, g = lane >> 4;
  const int rs = lo & 7;

  const int srow = tid >> 3, sgi = tid & 7;
  const int sgis = (sgi ^ (srow & 7)) * 8;
  const unsigned short* kbase = kk_ + ((size_t)bh * T_ + srow) * 64 + sgi * 8;
  const unsigned short* vbase = vt + ((size_t)(bh * 64 + srow)) * T_ + sgi * 8;

  #pragma unroll 1
  for (int half = 0; half < 2; ++half) {
    const int qt = half ? (31 - blockIdx.y) : blockIdx.y;
    const int t0 = qt * 64;
    const int tw = t0 + w * 16;

    bf16x8 qf[2];
    const unsigned short* qb = q + ((size_t)(bh * T_ + tw + lo)) * 64;
    #pragma unroll
    for (int kd = 0; kd < 2; ++kd)
      qf[kd] = *(const bf16x8*)(qb + kd * 32 + g * 8);

    float m_ = -1e30f, l_ = 0.f;
    f32x4 zero4 = {0.f, 0.f, 0.f, 0.f};
    f32x4 oacc[4];
    #pragma unroll
    for (int dt = 0; dt < 4; ++dt) oacc[dt] = zero4;

    const int nsteps = qt + 1;
    // prologue: stage step 0; preload step-1 regs
    us8 kr0 = *(const us8*)(kbase);
    us8 kr1 = *(const us8*)(kbase + 2048);
    us8 vr0 = *(const us8*)(vbase);
    us8 vr1 = *(const us8*)(vbase + (size_t)32 * T_);
    __syncthreads();  // protect previous tile's epilogue PV reads of Vl
    *(us8*)&Kl[0][srow][sgis] = kr0;
    *(us8*)&Kl[0][srow + 32][sgis] = kr1;
    *(us8*)&Vl[0][srow][sgis] = vr0;
    *(us8*)&Vl[0][srow + 32][sgis] = vr1;
    if (nsteps > 1) {
      kr0 = *(const us8*)(kbase + 4096);
      kr1 = *(const us8*)(kbase + 4096 + 2048);
      vr0 = *(const us8*)(vbase + 64);
      vr1 = *(const us8*)(vbase + 64 + (size_t)32 * T_);
    }
    __syncthreads();

    bf16x8 pb[2];     // previous step's P fragments (registers)
    int vprev = 0;    // V buffer holding V(stp-1)

    for (int stp = 0; stp < nsteps; ++stp) {
      const int cur = stp & 1;
      us8 nk0, nk1, nv0, nv1;
      const bool pf = (stp + 2 < nsteps);
      if (pf) {
        const size_t ko_ = (size_t)(stp + 2) * 4096;
        nk0 = *(const us8*)(kbase + ko_);
        nk1 = *(const us8*)(kbase + ko_ + 2048);
        nv0 = *(const us8*)(vbase + (stp + 2) * 64);
        nv1 = *(const us8*)(vbase + (stp + 2) * 64 + (size_t)32 * T_);
      }
      // ---- MFMA cluster: QK^T(stp) + PV(stp-1), mutually independent ----
      f32x4 sacc[4];
      #pragma unroll
      for (int ss = 0; ss < 4; ++ss) sacc[ss] = zero4;
      __builtin_amdgcn_s_setprio(1);
      #pragma unroll
      for (int ss = 0; ss < 4; ++ss) {
        bf16x8 ka0 = *(const bf16x8*)&Kl[cur][ss * 16 + lo][(g ^ rs) * 8];
        bf16x8 ka1 = *(const bf16x8*)&Kl[cur][ss * 16 + lo][((g | 4) ^ rs) * 8];
        sacc[ss] = mfma16(ka0, qf[0], sacc[ss]);
        sacc[ss] = mfma16(ka1, qf[1], sacc[ss]);
      }
      if (stp > 0) {
        #pragma unroll
        for (int kh = 0; kh < 2; ++kh) {
          #pragma unroll
          for (int dt = 0; dt < 4; ++dt) {
            bf16x8 va = *(const bf16x8*)&Vl[vprev][dt * 16 + lo][((kh * 4 + g) ^ rs) * 8];
            oacc[dt] = mfma16(va, pb[kh], oacc[dt]);
          }
        }
      }
      __builtin_amdgcn_s_setprio(0);
      // ---- softmax(stp) (VALU; overlaps MFMA drain) ----
      if (stp == nsteps - 1) {  // diagonal step: causal mask
        #pragma unroll
        for (int ss = 0; ss < 4; ++ss)
          #pragma unroll
          for (int r = 0; r < 4; ++r) {
            int sg = t0 + ss * 16 + g * 4 + r;
            if (sg > tw + lo) sacc[ss][r] = -1e30f;
          }
      }
      float mx = -1e30f;
      #pragma unroll
      for (int ss = 0; ss < 4; ++ss)
        #pragma unroll
        for (int r = 0; r < 4; ++r) mx = fmaxf(mx, sacc[ss][r]);
      mx = fmaxf(mx, __shfl_xor(mx, 16));
      mx = fmaxf(mx, __shfl_xor(mx, 32));
      if (!__all(mx <= m_ + 8.0f)) {  // defer-max: rare rescale (waits on PV)
        float mn = fmaxf(m_, mx);
        float corr = fexp2(m_ - mn);
        m_ = mn;
        l_ *= corr;
        #pragma unroll
        for (int dt = 0; dt < 4; ++dt) oacc[dt] *= corr;
      }
      float sum = 0.f;
      #pragma unroll
      for (int ss = 0; ss < 4; ++ss) {
        us4 pk;
        #pragma unroll
        for (int r = 0; r < 4; ++r) {
          float pv = fexp2(sacc[ss][r] - m_);
          sum += pv;
          pk[r] = f2b(pv);
        }
        *(us4*)&Pl[w][lo][(((ss * 2 + (g >> 1)) ^ rs) << 3) + (g & 1) * 4] = pk;
      }
      sum += __shfl_xor(sum, 16);
      sum += __shfl_xor(sum, 32);
      l_ += sum;
      // read back P(stp) fragments for next step's PV (wave-private, DS FIFO)
      pb[0] = *(const bf16x8*)&Pl[w][lo][(g ^ rs) * 8];
      pb[1] = *(const bf16x8*)&Pl[w][lo][((4 + g) ^ rs) * 8];
      vprev = stp % 3;
      // stage next K/V tile (regs loaded last iteration / prologue)
      if (stp + 1 < nsteps) {
        *(us8*)&Kl[cur ^ 1][srow][sgis] = kr0;
        *(us8*)&Kl[cur ^ 1][srow + 32][sgis] = kr1;
        const int vn = (stp + 1) % 3;
        *(us8*)&Vl[vn][srow][sgis] = vr0;
        *(us8*)&Vl[vn][srow + 32][sgis] = vr1;
      }
      __syncthreads();
      if (pf) { kr0 = nk0; kr1 = nk1; vr0 = nv0; vr1 = nv1; }
    }
    // epilogue: drain PV(last)
    __builtin_amdgcn_s_setprio(1);
    #pragma unroll
    for (int kh = 0; kh < 2; ++kh) {
      #pragma unroll
      for (int dt = 0; dt < 4; ++dt) {
        bf16x8 va = *(const bf16x8*)&Vl[vprev][dt * 16 + lo][((kh * 4 + g) ^ rs) * 8];
        oacc[dt] = mfma16(va, pb[kh], oacc[dt]);
      }
    }
    __builtin_amdgcn_s_setprio(0);
    float inv = 1.0f / l_;
    unsigned short* op = ao + ((size_t)(b * T_ + tw + lo)) * E_ + h * 64;
    #pragma unroll
    for (int dt = 0; dt < 4; ++dt) {
      us4 pk;
      #pragma unroll
      for (int r = 0; r < 4; ++r) pk[r] = f2b(oacc[dt][r] * inv);
      *(us4*)(op + dt * 16 + g * 4) = pk;
    }
  }
}

// ---------------- output projection (r5 verbatim) ----------------
__launch_bounds__(256)
__global__ void proj_kernel(const unsigned short* __restrict__ ao,
                            const unsigned short* __restrict__ wpb,
                            const float* __restrict__ bp,
                            float* __restrict__ out)
{
  const int m0 = blockIdx.x * 128;
  const int n0 = blockIdx.y * 64;
  __shared__ unsigned short Al[2][128][40];
  __shared__ unsigned short Bl[2][64][40];
  const int tid = threadIdx.x, w = tid >> 6, lane = tid & 63, lo = lane & 15, g = lane >> 4;
  const int wr = (w >> 1) * 64, wc = (w & 1) * 32;
  f32x4 zero4 = {0.f, 0.f, 0.f, 0.f};
  f32x4 acc[4][2];
  #pragma unroll
  for (int i = 0; i < 4; ++i)
    #pragma unroll
    for (int j = 0; j < 2; ++j) acc[i][j] = zero4;

  const int arow = tid >> 1, acol = (tid & 1) * 16;
  const int brow = tid >> 2, bcol = (tid & 3) * 8;
  const unsigned short* abase = ao + (size_t)(m0 + arow) * 1024 + acol;
  const unsigned short* bbase = wpb + (size_t)(n0 + brow) * 1024 + bcol;

  us8 a0 = *(const us8*)(abase);
  us8 a1 = *(const us8*)(abase + 8);
  us8 b0 = *(const us8*)(bbase);
  *(us8*)&Al[0][arow][acol] = a0;
  *(us8*)&Al[0][arow][acol + 8] = a1;
  *(us8*)&Bl[0][brow][bcol] = b0;
  a0 = *(const us8*)(abase + 32);
  a1 = *(const us8*)(abase + 40);
  b0 = *(const us8*)(bbase + 32);
  __syncthreads();

  for (int it = 0; it < 32; ++it) {
    const int cur = it & 1;
    us8 na0, na1, nb0;
    const bool pf = (it + 2 < 32);
    if (pf) {
      const int kn = (it + 2) * 32;
      na0 = *(const us8*)(abase + kn);
      na1 = *(const us8*)(abase + kn + 8);
      nb0 = *(const us8*)(bbase + kn);
    }
    bf16x8 af[4], bfr[2];
    #pragma unroll
    for (int i = 0; i < 4; ++i) af[i] = *(const bf16x8*)&Al[cur][wr + i * 16 + lo][g * 8];
    #pragma unroll
    for (int j = 0; j < 2; ++j) bfr[j] = *(const bf16x8*)&Bl[cur][wc + j * 16 + lo][g * 8];
    __builtin_amdgcn_s_setprio(1);
    #pragma unroll
    for (int i = 0; i < 4; ++i)
      #pragma unroll
      for (int j = 0; j < 2; ++j)
        acc[i][j] = mfma16(af[i], bfr[j], acc[i][j]);
    __builtin_amdgcn_s_setprio(0);
    if (it + 1 < 32) {
      *(us8*)&Al[cur ^ 1][arow][acol] = a0;
      *(us8*)&Al[cur ^ 1][arow][acol + 8] = a1;
      *(us8*)&Bl[cur ^ 1][brow][bcol] = b0;
    }
    __syncthreads();
    if (pf) { a0 = na0; a1 = na1; b0 = nb0; }
  }
  #pragma unroll
  for (int j = 0; j < 2; ++j) {
    int n = n0 + wc + j * 16 + lo;
    float bias = bp[n];
    #pragma unroll
    for (int i = 0; i < 4; ++i) {
      #pragma unroll
      for (int r = 0; r < 4; ++r)
        out[(size_t)(m0 + wr + i * 16 + g * 4 + r) * 1024 + n] = acc[i][j][r] + bias;
    }
  }
}

extern "C" void kernel_launch(void* const* d_in, const int* in_sizes, int n_in,
                              void* d_out, int out_size, void* d_ws, size_t ws_size,
                              hipStream_t stream)
{
  const float* x  = (const float*)d_in[0];
  const float* Wq = (const float*)d_in[2];
  const float* bq = (const float*)d_in[3];
  const float* Wk = (const float*)d_in[4];
  const float* bk = (const float*)d_in[5];
  const float* Wv = (const float*)d_in[6];
  const float* bv = (const float*)d_in[7];
  const float* Wp = (const float*)d_in[8];
  const float* bp = (const float*)d_in[9];
  float* out = (float*)d_out;

  char* ws = (char*)d_ws;
  const size_t SZ = (size_t)2 * 16 * 2048 * 64 * 2;  // 8 MB per bf16 tensor
  unsigned short* q  = (unsigned short*)(ws);
  unsigned short* kb = (unsigned short*)(ws + SZ);
  unsigned short* vt = (unsigned short*)(ws + 2 * SZ);
  unsigned short* ao = (unsigned short*)(ws + 3 * SZ);
  unsigned short* wqb = ao;                  // overlay: qkv reads before flash writes ao
  unsigned short* wkb = ao + 65536;
  unsigned short* wvb = ao + 131072;
  unsigned short* wpb = q;                   // overlay: wpcvt runs after flash read q

  wcvt_kernel<<<dim3(192), 256, 0, stream>>>(Wq, Wk, Wv, wqb, wkb, wvb);
  qkv_kernel<<<dim3(32, 16), 256, 0, stream>>>(x, wqb, bq, wkb, bk, wvb, bv, q, kb, vt);
  flash_kernel<<<dim3(32, 16), 256, 0, stream>>>(q, kb, vt, ao);
  wpcvt_kernel<<<dim3(1024), 256, 0, stream>>>(Wp, wpb);
  proj_kernel<<<dim3(32, 16), 256, 0, stream>>>(ao, wpb, bp, out);
}

// Round 8
// 79.334 us; speedup vs baseline: 1.2290x; 1.0591x over previous
//
#include <hip/hip_runtime.h>

typedef __attribute__((ext_vector_type(4))) float f32x4;
typedef __attribute__((ext_vector_type(8))) __bf16 bf16x8;
typedef __attribute__((ext_vector_type(4))) unsigned short us4;
typedef __attribute__((ext_vector_type(8))) unsigned short us8;

#define DEVI static __device__ __forceinline__

constexpr int T_ = 2048, E_ = 1024, H_ = 16, D_ = 64;
#define QSCALE (0.125f * 1.44269504088896f)  /* 1/sqrt(D) * log2(e) */

DEVI unsigned short f2b(float f) {
  union { __bf16 b; unsigned short u; } c; c.b = (__bf16)f; return c.u;
}

#if __has_builtin(__builtin_amdgcn_exp2f)
DEVI float fexp2(float x) { return __builtin_amdgcn_exp2f(x); }
#else
DEVI float fexp2(float x) { return __expf(x * 0.69314718056f); }
#endif

DEVI f32x4 mfma16(bf16x8 a, bf16x8 b, f32x4 c) {
  return __builtin_amdgcn_mfma_f32_16x16x32_bf16(a, b, c, 0, 0, 0);
}

// ---------------- weight conversion kernels (run once) ----------------
__launch_bounds__(256)
__global__ void wcvt_kernel(const float* __restrict__ Wq,
                            const float* __restrict__ Wk,
                            const float* __restrict__ Wv,
                            unsigned short* __restrict__ wqb,
                            unsigned short* __restrict__ wkb,
                            unsigned short* __restrict__ wvb)
{
  int blk = blockIdx.x;
  const float* src; unsigned short* dst; float s = 1.0f;
  if (blk < 64)       { src = Wq; dst = wqb; s = QSCALE; }
  else if (blk < 128) { src = Wk; dst = wkb; blk -= 64; }
  else                { src = Wv; dst = wvb; blk -= 128; }
  int i = blk * 256 + threadIdx.x;
  float4 v = *(const float4*)(src + (size_t)i * 4);
  us4 o; o[0] = f2b(v.x * s); o[1] = f2b(v.y * s); o[2] = f2b(v.z * s); o[3] = f2b(v.w * s);
  *(us4*)(dst + (size_t)i * 4) = o;
}

__launch_bounds__(256)
__global__ void wpcvt_kernel(const float* __restrict__ Wp,
                             unsigned short* __restrict__ wpb)
{
  int i = blockIdx.x * 256 + threadIdx.x;
  float4 v = *(const float4*)(Wp + (size_t)i * 4);
  us4 o; o[0] = f2b(v.x); o[1] = f2b(v.y); o[2] = f2b(v.z); o[3] = f2b(v.w);
  *(us4*)(wpb + (size_t)i * 4) = o;
}

// ---------------- QKV projection (r5 verbatim) ----------------
__launch_bounds__(256)
__global__ void qkv_kernel(const float* __restrict__ x,
                           const unsigned short* __restrict__ wqb,
                           const float* __restrict__ bq,
                           const unsigned short* __restrict__ wkb,
                           const float* __restrict__ bk,
                           const unsigned short* __restrict__ wvb,
                           const float* __restrict__ bv,
                           unsigned short* __restrict__ qo,
                           unsigned short* __restrict__ ko,
                           unsigned short* __restrict__ vto)
{
  const int bh = blockIdx.x;
  const int b  = bh >> 4;
  const int h  = bh & (H_ - 1);
  const int t0 = blockIdx.y * 128;
  __shared__ unsigned short Xl[128][72];
  __shared__ unsigned short Wl[3][64][72];
  const int tid = threadIdx.x;

  #pragma unroll
  for (int p = 0; p < 8; ++p) {
    int idx = p * 256 + tid;
    int row = idx >> 4, c4 = idx & 15;
    float4 v = *(const float4*)(x + ((size_t)(b * T_ + t0 + row)) * E_ + h * 64 + c4 * 4);
    us4 o; o[0] = f2b(v.x); o[1] = f2b(v.y); o[2] = f2b(v.z); o[3] = f2b(v.w);
    *(us4*)&Xl[row][c4 * 4] = o;
  }
  {
    const unsigned short* wsrc0 = wqb + (size_t)h * 4096;
    const unsigned short* wsrc1 = wkb + (size_t)h * 4096;
    const unsigned short* wsrc2 = wvb + (size_t)h * 4096;
    #pragma unroll
    for (int p = 0; p < 2; ++p) {
      int idx = p * 256 + tid;
      int row = idx >> 3, c8 = (idx & 7) * 8;
      *(us8*)&Wl[0][row][c8] = *(const us8*)(wsrc0 + row * 64 + c8);
      *(us8*)&Wl[1][row][c8] = *(const us8*)(wsrc1 + row * 64 + c8);
      *(us8*)&Wl[2][row][c8] = *(const us8*)(wsrc2 + row * 64 + c8);
    }
  }
  __syncthreads();

  const int w = tid >> 6, lane = tid & 63, lo = lane & 15, g = lane >> 4;
  const int tl0 = w * 32;

  bf16x8 xb[2][2];
  #pragma unroll
  for (int tt = 0; tt < 2; ++tt)
    #pragma unroll
    for (int kd = 0; kd < 2; ++kd)
      xb[tt][kd] = *(const bf16x8*)&Xl[tl0 + tt * 16 + lo][kd * 32 + g * 8];

  #pragma unroll
  for (int tsel = 0; tsel < 2; ++tsel) {
    const float* bias = tsel ? bk : bq;
    unsigned short* outp = tsel ? ko : qo;
    const float bs = tsel ? 1.0f : QSCALE;
    #pragma unroll
    for (int ot = 0; ot < 4; ++ot) {
      bf16x8 a0 = *(const bf16x8*)&Wl[tsel][ot * 16 + lo][g * 8];
      bf16x8 a1 = *(const bf16x8*)&Wl[tsel][ot * 16 + lo][32 + g * 8];
      float4 bv4 = *(const float4*)(bias + h * 64 + ot * 16 + g * 4);
      float bb[4] = {bv4.x * bs, bv4.y * bs, bv4.z * bs, bv4.w * bs};
      #pragma unroll
      for (int tt = 0; tt < 2; ++tt) {
        f32x4 acc = {0.f, 0.f, 0.f, 0.f};
        acc = mfma16(a0, xb[tt][0], acc);
        acc = mfma16(a1, xb[tt][1], acc);
        int tg = t0 + tl0 + tt * 16 + lo;
        us4 pk;
        #pragma unroll
        for (int r = 0; r < 4; ++r) pk[r] = f2b(acc[r] + bb[r]);
        *(us4*)(outp + ((size_t)(bh * T_ + tg)) * 64 + ot * 16 + g * 4) = pk;
      }
    }
  }

  #pragma unroll
  for (int rt = 0; rt < 2; ++rt) {
    bf16x8 a0 = *(const bf16x8*)&Xl[tl0 + rt * 16 + lo][g * 8];
    bf16x8 a1 = *(const bf16x8*)&Xl[tl0 + rt * 16 + lo][32 + g * 8];
    #pragma unroll
    for (int ct = 0; ct < 4; ++ct) {
      bf16x8 b0 = *(const bf16x8*)&Wl[2][ct * 16 + lo][g * 8];
      bf16x8 b1 = *(const bf16x8*)&Wl[2][ct * 16 + lo][32 + g * 8];
      f32x4 acc = {0.f, 0.f, 0.f, 0.f};
      acc = mfma16(a0, b0, acc);
      acc = mfma16(a1, b1, acc);
      int d = ct * 16 + lo;
      float bvs = bv[h * 64 + d];
      int tg = t0 + tl0 + rt * 16 + g * 4;
      us4 pk;
      #pragma unroll
      for (int r = 0; r < 4; ++r) pk[r] = f2b(acc[r] + bvs);
      *(us4*)(vto + ((size_t)(bh * 64 + d)) * T_ + tg) = pk;
    }
  }
}

// ---------------- causal flash attention ----------------
// grid: (B*H=32, 32), block 256 = 4 waves x 16 q-rows, one 64-row q-tile per
// block, qt = 31 - blockIdx.y (heavy blocks dispatch first; short ones
// backfill the tail). 48KB LDS -> 3 blocks/CU = 12 waves. Deferred PV (T15);
// NO cross-lane ops on the common softmax path: per-lane defer-max check
// (T13) and per-lane l partials reduced once in the epilogue.
__launch_bounds__(256)
__global__ void flash_kernel(const unsigned short* __restrict__ q,
                             const unsigned short* __restrict__ kk_,
                             const unsigned short* __restrict__ vt,
                             unsigned short* __restrict__ ao)
{
  const int bh = blockIdx.x;
  const int b = bh >> 4, h = bh & 15;
  const int qt = 31 - blockIdx.y;
  const int t0 = qt * 64;
  __shared__ unsigned short Kl[2][64][64];
  __shared__ unsigned short Vl[3][64][64];
  __shared__ unsigned short Pl[4][16][64];
  const int tid = threadIdx.x, w = tid >> 6, lane = tid & 63, lo = lane & 15, g = lane >> 4;
  const int rs = lo & 7;

  const int srow = tid >> 3, sgi = tid & 7;
  const int sgis = (sgi ^ (srow & 7)) * 8;
  const unsigned short* kbase = kk_ + ((size_t)bh * T_ + srow) * 64 + sgi * 8;
  const unsigned short* vbase = vt + ((size_t)(bh * 64 + srow)) * T_ + sgi * 8;

  const int tw = t0 + w * 16;

  bf16x8 qf[2];
  const unsigned short* qb = q + ((size_t)(bh * T_ + tw + lo)) * 64;
  #pragma unroll
  for (int kd = 0; kd < 2; ++kd)
    qf[kd] = *(const bf16x8*)(qb + kd * 32 + g * 8);

  float m_ = -1e30f, l_ = 0.f;
  f32x4 zero4 = {0.f, 0.f, 0.f, 0.f};
  f32x4 oacc[4];
  #pragma unroll
  for (int dt = 0; dt < 4; ++dt) oacc[dt] = zero4;

  const int nsteps = qt + 1;
  // prologue: stage step 0; preload step-1 regs
  us8 kr0 = *(const us8*)(kbase);
  us8 kr1 = *(const us8*)(kbase + 2048);
  us8 vr0 = *(const us8*)(vbase);
  us8 vr1 = *(const us8*)(vbase + (size_t)32 * T_);
  *(us8*)&Kl[0][srow][sgis] = kr0;
  *(us8*)&Kl[0][srow + 32][sgis] = kr1;
  *(us8*)&Vl[0][srow][sgis] = vr0;
  *(us8*)&Vl[0][srow + 32][sgis] = vr1;
  if (nsteps > 1) {
    kr0 = *(const us8*)(kbase + 4096);
    kr1 = *(const us8*)(kbase + 4096 + 2048);
    vr0 = *(const us8*)(vbase + 64);
    vr1 = *(const us8*)(vbase + 64 + (size_t)32 * T_);
  }
  __syncthreads();

  bf16x8 pb[2];     // previous step's P fragments (registers)
  int vprev = 0;    // V buffer holding V(stp-1)

  for (int stp = 0; stp < nsteps; ++stp) {
    const int cur = stp & 1;
    us8 nk0, nk1, nv0, nv1;
    const bool pf = (stp + 2 < nsteps);
    if (pf) {
      const size_t ko_ = (size_t)(stp + 2) * 4096;
      nk0 = *(const us8*)(kbase + ko_);
      nk1 = *(const us8*)(kbase + ko_ + 2048);
      nv0 = *(const us8*)(vbase + (stp + 2) * 64);
      nv1 = *(const us8*)(vbase + (stp + 2) * 64 + (size_t)32 * T_);
    }
    // ---- MFMA cluster: QK^T(stp) + PV(stp-1), mutually independent ----
    f32x4 sacc[4];
    #pragma unroll
    for (int ss = 0; ss < 4; ++ss) sacc[ss] = zero4;
    __builtin_amdgcn_s_setprio(1);
    #pragma unroll
    for (int ss = 0; ss < 4; ++ss) {
      bf16x8 ka0 = *(const bf16x8*)&Kl[cur][ss * 16 + lo][(g ^ rs) * 8];
      bf16x8 ka1 = *(const bf16x8*)&Kl[cur][ss * 16 + lo][((g | 4) ^ rs) * 8];
      sacc[ss] = mfma16(ka0, qf[0], sacc[ss]);
      sacc[ss] = mfma16(ka1, qf[1], sacc[ss]);
    }
    if (stp > 0) {
      #pragma unroll
      for (int kh = 0; kh < 2; ++kh) {
        #pragma unroll
        for (int dt = 0; dt < 4; ++dt) {
          bf16x8 va = *(const bf16x8*)&Vl[vprev][dt * 16 + lo][((kh * 4 + g) ^ rs) * 8];
          oacc[dt] = mfma16(va, pb[kh], oacc[dt]);
        }
      }
    }
    __builtin_amdgcn_s_setprio(0);
    // ---- softmax(stp): no cross-lane ops on the common path ----
    if (stp == nsteps - 1) {  // diagonal step: causal mask
      #pragma unroll
      for (int ss = 0; ss < 4; ++ss)
        #pragma unroll
        for (int r = 0; r < 4; ++r) {
          int sg = t0 + ss * 16 + g * 4 + r;
          if (sg > tw + lo) sacc[ss][r] = -1e30f;
        }
    }
    // per-lane max over this lane's 16 S values
    float mx = -1e30f;
    #pragma unroll
    for (int ss = 0; ss < 4; ++ss) {
      float a = fmaxf(sacc[ss][0], sacc[ss][1]);
      float c = fmaxf(sacc[ss][2], sacc[ss][3]);
      mx = fmaxf(mx, fmaxf(a, c));
    }
    // defer-max: global max <= m_+8  <=>  all lanes' maxes <= m_+8
    if (!__all(mx <= m_ + 8.0f)) {  // rare rescale (wave-uniform branch)
      mx = fmaxf(mx, __shfl_xor(mx, 16));
      mx = fmaxf(mx, __shfl_xor(mx, 32));
      float mn = fmaxf(m_, mx);
      float corr = fexp2(m_ - mn);
      m_ = mn;   // uniform across g-groups (global value)
      l_ *= corr;
      #pragma unroll
      for (int dt = 0; dt < 4; ++dt) oacc[dt] *= corr;
    }
    float sum = 0.f;
    #pragma unroll
    for (int ss = 0; ss < 4; ++ss) {
      us4 pk;
      #pragma unroll
      for (int r = 0; r < 4; ++r) {
        float pv = fexp2(sacc[ss][r] - m_);
        sum += pv;
        pk[r] = f2b(pv);
      }
      *(us4*)&Pl[w][lo][(((ss * 2 + (g >> 1)) ^ rs) << 3) + (g & 1) * 4] = pk;
    }
    l_ += sum;  // per-lane partial; cross-lane reduce deferred to epilogue
    // read back P(stp) fragments for next step's PV (wave-private)
    pb[0] = *(const bf16x8*)&Pl[w][lo][(g ^ rs) * 8];
    pb[1] = *(const bf16x8*)&Pl[w][lo][((4 + g) ^ rs) * 8];
    vprev = stp % 3;
    // stage next K/V tile (regs loaded last iteration / prologue)
    if (stp + 1 < nsteps) {
      *(us8*)&Kl[cur ^ 1][srow][sgis] = kr0;
      *(us8*)&Kl[cur ^ 1][srow + 32][sgis] = kr1;
      const int vn = (stp + 1) % 3;
      *(us8*)&Vl[vn][srow][sgis] = vr0;
      *(us8*)&Vl[vn][srow + 32][sgis] = vr1;
    }
    __syncthreads();
    if (pf) { kr0 = nk0; kr1 = nk1; vr0 = nv0; vr1 = nv1; }
  }
  // epilogue: drain PV(last), reduce l across g-groups
  __builtin_amdgcn_s_setprio(1);
  #pragma unroll
  for (int kh = 0; kh < 2; ++kh) {
    #pragma unroll
    for (int dt = 0; dt < 4; ++dt) {
      bf16x8 va = *(const bf16x8*)&Vl[vprev][dt * 16 + lo][((kh * 4 + g) ^ rs) * 8];
      oacc[dt] = mfma16(va, pb[kh], oacc[dt]);
    }
  }
  __builtin_amdgcn_s_setprio(0);
  l_ += __shfl_xor(l_, 16);
  l_ += __shfl_xor(l_, 32);
  float inv = 1.0f / l_;
  unsigned short* op = ao + ((size_t)(b * T_ + tw + lo)) * E_ + h * 64;
  #pragma unroll
  for (int dt = 0; dt < 4; ++dt) {
    us4 pk;
    #pragma unroll
    for (int r = 0; r < 4; ++r) pk[r] = f2b(oacc[dt][r] * inv);
    *(us4*)(op + dt * 16 + g * 4) = pk;
  }
}

// ---------------- output projection (r5 verbatim) ----------------
__launch_bounds__(256)
__global__ void proj_kernel(const unsigned short* __restrict__ ao,
                            const unsigned short* __restrict__ wpb,
                            const float* __restrict__ bp,
                            float* __restrict__ out)
{
  const int m0 = blockIdx.x * 128;
  const int n0 = blockIdx.y * 64;
  __shared__ unsigned short Al[2][128][40];
  __shared__ unsigned short Bl[2][64][40];
  const int tid = threadIdx.x, w = tid >> 6, lane = tid & 63, lo = lane & 15, g = lane >> 4;
  const int wr = (w >> 1) * 64, wc = (w & 1) * 32;
  f32x4 zero4 = {0.f, 0.f, 0.f, 0.f};
  f32x4 acc[4][2];
  #pragma unroll
  for (int i = 0; i < 4; ++i)
    #pragma unroll
    for (int j = 0; j < 2; ++j) acc[i][j] = zero4;

  const int arow = tid >> 1, acol = (tid & 1) * 16;
  const int brow = tid >> 2, bcol = (tid & 3) * 8;
  const unsigned short* abase = ao + (size_t)(m0 + arow) * 1024 + acol;
  const unsigned short* bbase = wpb + (size_t)(n0 + brow) * 1024 + bcol;

  us8 a0 = *(const us8*)(abase);
  us8 a1 = *(const us8*)(abase + 8);
  us8 b0 = *(const us8*)(bbase);
  *(us8*)&Al[0][arow][acol] = a0;
  *(us8*)&Al[0][arow][acol + 8] = a1;
  *(us8*)&Bl[0][brow][bcol] = b0;
  a0 = *(const us8*)(abase + 32);
  a1 = *(const us8*)(abase + 40);
  b0 = *(const us8*)(bbase + 32);
  __syncthreads();

  for (int it = 0; it < 32; ++it) {
    const int cur = it & 1;
    us8 na0, na1, nb0;
    const bool pf = (it + 2 < 32);
    if (pf) {
      const int kn = (it + 2) * 32;
      na0 = *(const us8*)(abase + kn);
      na1 = *(const us8*)(abase + kn + 8);
      nb0 = *(const us8*)(bbase + kn);
    }
    bf16x8 af[4], bfr[2];
    #pragma unroll
    for (int i = 0; i < 4; ++i) af[i] = *(const bf16x8*)&Al[cur][wr + i * 16 + lo][g * 8];
    #pragma unroll
    for (int j = 0; j < 2; ++j) bfr[j] = *(const bf16x8*)&Bl[cur][wc + j * 16 + lo][g * 8];
    __builtin_amdgcn_s_setprio(1);
    #pragma unroll
    for (int i = 0; i < 4; ++i)
      #pragma unroll
      for (int j = 0; j < 2; ++j)
        acc[i][j] = mfma16(af[i], bfr[j], acc[i][j]);
    __builtin_amdgcn_s_setprio(0);
    if (it + 1 < 32) {
      *(us8*)&Al[cur ^ 1][arow][acol] = a0;
      *(us8*)&Al[cur ^ 1][arow][acol + 8] = a1;
      *(us8*)&Bl[cur ^ 1][brow][bcol] = b0;
    }
    __syncthreads();
    if (pf) { a0 = na0; a1 = na1; b0 = nb0; }
  }
  #pragma unroll
  for (int j = 0; j < 2; ++j) {
    int n = n0 + wc + j * 16 + lo;
    float bias = bp[n];
    #pragma unroll
    for (int i = 0; i < 4; ++i) {
      #pragma unroll
      for (int r = 0; r < 4; ++r)
        out[(size_t)(m0 + wr + i * 16 + g * 4 + r) * 1024 + n] = acc[i][j][r] + bias;
    }
  }
}

extern "C" void kernel_launch(void* const* d_in, const int* in_sizes, int n_in,
                              void* d_out, int out_size, void* d_ws, size_t ws_size,
                              hipStream_t stream)
{
  const float* x  = (const float*)d_in[0];
  const float* Wq = (const float*)d_in[2];
  const float* bq = (const float*)d_in[3];
  const float* Wk = (const float*)d_in[4];
  const float* bk = (const float*)d_in[5];
  const float* Wv = (const float*)d_in[6];
  const float* bv = (const float*)d_in[7];
  const float* Wp = (const float*)d_in[8];
  const float* bp = (const float*)d_in[9];
  float* out = (float*)d_out;

  char* ws = (char*)d_ws;
  const size_t SZ = (size_t)2 * 16 * 2048 * 64 * 2;  // 8 MB per bf16 tensor
  unsigned short* q  = (unsigned short*)(ws);
  unsigned short* kb = (unsigned short*)(ws + SZ);
  unsigned short* vt = (unsigned short*)(ws + 2 * SZ);
  unsigned short* ao = (unsigned short*)(ws + 3 * SZ);
  unsigned short* wqb = ao;                  // overlay: qkv reads before flash writes ao
  unsigned short* wkb = ao + 65536;
  unsigned short* wvb = ao + 131072;
  unsigned short* wpb = q;                   // overlay: wpcvt runs after flash read q

  wcvt_kernel<<<dim3(192), 256, 0, stream>>>(Wq, Wk, Wv, wqb, wkb, wvb);
  qkv_kernel<<<dim3(32, 16), 256, 0, stream>>>(x, wqb, bq, wkb, bk, wvb, bv, q, kb, vt);
  flash_kernel<<<dim3(32, 32), 256, 0, stream>>>(q, kb, vt, ao);
  wpcvt_kernel<<<dim3(1024), 256, 0, stream>>>(Wp, wpb);
  proj_kernel<<<dim3(32, 16), 256, 0, stream>>>(ao, wpb, bp, out);
}